// Round 9
// baseline (4350.377 us; speedup 1.0000x reference)
//
#include <hip/hip_runtime.h>
#include <math.h>

#define BB 64
#define TT 512
#define FF 512
#define DIN 1024
#define HH 1024
#define G4 4096
#define DOUT 128

typedef _Float16 f16;
typedef _Float16 f16x4 __attribute__((ext_vector_type(4)));
typedef _Float16 f16x8 __attribute__((ext_vector_type(8)));
typedef float f32x2 __attribute__((ext_vector_type(2)));
typedef float f32x4 __attribute__((ext_vector_type(4)));

// A-fragment-linear layout for a [64 x 1024] fp16 activation matrix:
//   element (m, k) -> ((k>>5)*4 + (m>>4))*512 + ((((k>>3)&3)<<4) | (m&15))*8 + (k&7)
__device__ __forceinline__ size_t afrag_off(int m, int k) {
    return (size_t)(((k >> 5) * 4 + (m >> 4)) * 512 + (((((k >> 3) & 3) << 4) | (m & 15)) * 8) + (k & 7));
}

// agent-scope write-through 8-B store (IF authoritative for cross-XCD readers)
__device__ __forceinline__ void store_b64_sc1(void* p, f32x2 v) {
    asm volatile("global_store_dwordx2 %0, %1, off sc1" :: "v"(p), "v"(v) : "memory");
}

// spin until *w >= tgt (agent scope, one cacheline per wave)
__device__ __forceinline__ void wave_wait(const unsigned* w, unsigned tgt) {
    while (__hip_atomic_load(w, __ATOMIC_RELAXED, __HIP_MEMORY_SCOPE_AGENT) < tgt)
        __builtin_amdgcn_s_sleep(1);
}

// ---------------------------------------------------------------------------
// Pack cat(W,U) [2048 x 4096] fp32 -> fp16 B-fragment-linear, z-cols reordered
// as col' = j*4 + g. Per (cg, kstep) a contiguous 1KB fragment tile.
// ---------------------------------------------------------------------------
__global__ __launch_bounds__(64) void k_pack(
    const float* __restrict__ W, const float* __restrict__ U, f16* __restrict__ out)
{
    const int kstep = blockIdx.x, cg = blockIdx.y, l = threadIdx.x;
    const int n = l & 15, q = l >> 4;
    const int stdcol = (n & 3) * HH + cg * 4 + (n >> 2);
    f16x8 v;
#pragma unroll
    for (int e = 0; e < 8; ++e) {
        int k = kstep * 32 + q * 8 + e;
        float s = (k < DIN) ? W[(size_t)k * G4 + stdcol] : U[(size_t)(k - DIN) * G4 + stdcol];
        v[e] = (f16)s;
    }
    *(f16x8*)(out + ((size_t)(cg * 64 + kstep) * 64 + l) * 8) = v;
}

// ---------------------------------------------------------------------------
// Pack Wi [512 x 1024] fp32 -> fp16 B-frag (no gate reorder). Tile (nt, kstep).
// ---------------------------------------------------------------------------
__global__ __launch_bounds__(64) void k_pack_wi(
    const float* __restrict__ Wi, f16* __restrict__ out)
{
    const int kstep = blockIdx.x;   // 0..15
    const int nt    = blockIdx.y;   // 0..63
    const int l = threadIdx.x;
    const int n = nt * 16 + (l & 15), q = l >> 4;
    f16x8 v;
#pragma unroll
    for (int e = 0; e < 8; ++e)
        v[e] = (f16)Wi[(size_t)(kstep * 32 + q * 8 + e) * DIN + n];
    *(f16x8*)(out + ((size_t)(nt * 16 + kstep) * 64 + l) * 8) = v;
}

// ---------------------------------------------------------------------------
// MFMA input dense: XinF[t] = tanh(x[:,t,:] @ Wi + bi), f16 A-frag layout.
// ---------------------------------------------------------------------------
__global__ __launch_bounds__(256) void k_dense_in2(
    const float* __restrict__ x, const f16* __restrict__ pWi,
    const float* __restrict__ bi, f16* __restrict__ XinF)
{
    extern __shared__ f16 xs[];   // 64 x 520 = 66560 B
    const int t = blockIdx.x;
    const int tid = threadIdx.x;

#pragma unroll
    for (int it = 0; it < 32; ++it) {
        int idx = tid + it * 256;
        int r = idx >> 7, c4 = idx & 127;
        float4 v = *(const float4*)(x + ((size_t)r * TT + t) * FF + c4 * 4);
        f16x4 hv = {(f16)v.x, (f16)v.y, (f16)v.z, (f16)v.w};
        *(f16x4*)(xs + (size_t)r * 520 + c4 * 4) = hv;
    }
    __syncthreads();

    const int w = tid >> 6, lane = tid & 63;
    const int col = lane & 15, rq = lane >> 4;
#pragma unroll 1
    for (int g = 0; g < 4; ++g) {
        f32x4 acc[4][4];
#pragma unroll
        for (int a = 0; a < 4; ++a)
#pragma unroll
            for (int b = 0; b < 4; ++b) acc[a][b] = (f32x4){0.f, 0.f, 0.f, 0.f};
#pragma unroll 2
        for (int ks2 = 0; ks2 < 16; ++ks2) {
            f16x8 bf[4];
#pragma unroll
            for (int nn = 0; nn < 4; ++nn)
                bf[nn] = *(const f16x8*)(pWi + ((size_t)((w * 16 + g * 4 + nn) * 16 + ks2) * 64 + lane) * 8);
#pragma unroll
            for (int mt = 0; mt < 4; ++mt) {
                f16x8 af = *(const f16x8*)(xs + (size_t)(mt * 16 + col) * 520 + ks2 * 32 + rq * 8);
#pragma unroll
                for (int nn = 0; nn < 4; ++nn)
                    acc[mt][nn] = __builtin_amdgcn_mfma_f32_16x16x32_f16(af, bf[nn], acc[mt][nn], 0, 0, 0);
            }
        }
#pragma unroll
        for (int nn = 0; nn < 4; ++nn) {
            const int j = (w * 16 + g * 4 + nn) * 16 + col;
            const float bb = bi[j];
#pragma unroll
            for (int mt = 0; mt < 4; ++mt)
#pragma unroll
                for (int r = 0; r < 4; ++r)
                    XinF[(size_t)t * (BB * DIN) + afrag_off(mt * 16 + rq * 4 + r, j)]
                        = (f16)tanhf(acc[mt][nn][r] + bb);
        }
    }
}

// ---------------------------------------------------------------------------
// Persistent kernel, 256 blocks x 512 threads (1 block/CU).
// lay = bid&1, cgb = bid>>1 (8 hidden units = 2 N-tiles). Weights in LDS once.
// PER-WAVE dependency gating:
//   L0: waves kq<2 consume static Xin -> no wait; waves kq>=2 wait go0>=p.
//   L1: waves kq<2 wait go0>=p (usually pre-satisfied: L0 runs ahead);
//       waves kq>=2 wait go1>=p. Each wave polls ONE go word.
// h: write-once history; per-epilogue-round 8-B sc1 write-through stores so
// round-0's drain overlaps round-1's compute. Only wave 0 (owner of all
// h-stores) drains vmcnt before the arrival flag; no end-of-phase barrier.
// Arrivals on own flag word (64-B stride); per-layer master (cgb==0, wave 0)
// aggregates 128 arrivals and publishes go.
// ---------------------------------------------------------------------------
__global__ __launch_bounds__(512, 2) void k_persist(
    const f16* __restrict__ XinF,
    f16* __restrict__ h0b_, f16* __restrict__ h1b_,
    const f16* __restrict__ pW0, const f16* __restrict__ pW1,
    const float* __restrict__ b0, const float* __restrict__ b1,
    unsigned* __restrict__ flags)
{
    extern __shared__ char smem[];
    f16*   bsh  = (f16*)smem;                     // 131072 B weight fragments
    float* red  = (float*)(smem + 131072);        // 16 tiles x 260 floats
    f16*   hrow = (f16*)(smem + 131072 + 16640);  // 2 rounds x 256 halves

    const int lay = blockIdx.x & 1;
    const int cgb = blockIdx.x >> 1;
    const int tid = threadIdx.x;
    const int wv = tid >> 6, lane = tid & 63;
    const int kq = wv >> 1, mh = wv & 1;

    unsigned* fl  = flags + (lay ? 2048 : 0);     // own-layer arrivals, stride 16
    unsigned* go0 = flags + 4096;
    unsigned* go1 = flags + 4096 + 16;
    unsigned* goMine = lay ? go1 : go0;

    // ---- stage this block's weight slice into LDS (once) ----
    {
        const f16x8* s8 = (const f16x8*)((lay ? pW1 : pW0) + (size_t)(cgb * 2) * 64 * 512);
        f16x8* d8 = (f16x8*)bsh;
#pragma unroll
        for (int it = 0; it < 16; ++it) d8[tid + it * 512] = s8[tid + it * 512];
    }

    // ---- epilogue-role constants ----
    const float* bias = lay ? b1 : b0;
    const int erow = tid & 63, ejl = (tid >> 6) & 3;
    const int emt = erow >> 4, esub = erow & 15;
    const int eslq = (esub >> 2) << 4, ereg = esub & 3;
    float bz[2][4];
    float creg[2] = {0.f, 0.f};
    if (tid < 256) {
#pragma unroll
        for (int n = 0; n < 2; ++n) {
            const int jg = (cgb * 2 + n) * 4 + ejl;
#pragma unroll
            for (int g = 0; g < 4; ++g) bz[n][g] = bias[g * HH + jg];
        }
    }

    const size_t HBUF = (size_t)BB * DIN;
    const f16* bq = bsh + (size_t)(kq * 16 * 64 + lane) * 8;
    __syncthreads();

    for (int p = 0; p <= TT; ++p) {
        if (lay == 0 && p == TT) break;            // L0 does phases 0..511
        const bool active = lay ? (p >= 1) : true;

        if (active) {
            const f16 *A1, *A2;
            f16* hw;
            if (lay == 0) {
                A1 = XinF + (size_t)p * HBUF;           // static input
                A2 = h0b_ + (size_t)p * HBUF;           // h0[p-1], needs go0>=p
                hw = h0b_ + (size_t)(p + 1) * HBUF;
            } else {
                A1 = h0b_ + (size_t)p * HBUF;           // h0[p-1], needs go0>=p
                A2 = h1b_ + (size_t)(p - 1) * HBUF;     // h1[p-2], needs go1>=p
                hw = h1b_ + (size_t)p * HBUF;
            }
            const f16* Ap = ((kq < 2) ? A1 : A2)
                          + (size_t)(((kq & 1) * 64 + mh * 2) * 512) + (size_t)lane * 8;

            // ---- per-wave dependency gate ----
            if (lay == 0) {
                if (kq >= 2 && p > 0) wave_wait(go0, (unsigned)p);
            } else {
                wave_wait(kq < 2 ? go0 : go1, (unsigned)p);
            }

            f32x4 acc00 = {0.f,0.f,0.f,0.f}, acc01 = {0.f,0.f,0.f,0.f};
            f32x4 acc10 = {0.f,0.f,0.f,0.f}, acc11 = {0.f,0.f,0.f,0.f};
#pragma unroll
            for (int ii = 0; ii < 16; ++ii) {
                f16x8 a0  = *(const f16x8*)(Ap + (size_t)(ii * 4) * 512);
                f16x8 a1  = *(const f16x8*)(Ap + (size_t)(ii * 4 + 1) * 512);
                f16x8 bb0 = *(const f16x8*)(bq + (size_t)ii * 512);
                f16x8 bb1 = *(const f16x8*)(bq + 32768 + (size_t)ii * 512);
                acc00 = __builtin_amdgcn_mfma_f32_16x16x32_f16(a0, bb0, acc00, 0, 0, 0);
                acc01 = __builtin_amdgcn_mfma_f32_16x16x32_f16(a0, bb1, acc01, 0, 0, 0);
                acc10 = __builtin_amdgcn_mfma_f32_16x16x32_f16(a1, bb0, acc10, 0, 0, 0);
                acc11 = __builtin_amdgcn_mfma_f32_16x16x32_f16(a1, bb1, acc11, 0, 0, 0);
            }

            // ---- two epilogue rounds; round-n h-stores (8B) overlap round n+1 ----
#pragma unroll
            for (int n = 0; n < 2; ++n) {
                f32x4 t0 = n ? acc01 : acc00;
                f32x4 t1 = n ? acc11 : acc10;
                *(f32x4*)(red + (size_t)(kq * 4 + mh * 2)     * 260 + lane * 4) = t0;
                *(f32x4*)(red + (size_t)(kq * 4 + mh * 2 + 1) * 260 + lane * 4) = t1;
                __syncthreads();
                if (tid < 256) {
                    float z[4];
#pragma unroll
                    for (int g = 0; g < 4; ++g) {
                        const int sl = eslq | (ejl * 4 + g);
                        float s = 0.f;
#pragma unroll
                        for (int k2 = 0; k2 < 4; ++k2)
                            s += red[(size_t)(k2 * 4 + emt) * 260 + sl * 4 + ereg];
                        z[g] = s + bz[n][g];
                    }
                    const float ig = 1.f / (1.f + expf(-z[0]));
                    const float fg = 1.f / (1.f + expf(-z[1]));
                    const float cc = tanhf(z[2]);
                    const float og = 1.f / (1.f + expf(-z[3]));
                    const float cn = fg * creg[n] + ig * cc;
                    creg[n] = cn;
                    hrow[n * 256 + erow * 4 + ejl] = (f16)(og * tanhf(cn));
                }
                __syncthreads();
                if (tid < 64) {
                    f32x2 v = *(f32x2*)(hrow + n * 256 + tid * 4);
                    store_b64_sc1(hw + afrag_off(tid, cgb * 8 + n * 4), v);
                }
            }
        }

        // ---- arrival: wave 0 owns all h-stores; drain then flag ----
        const unsigned tgt = (unsigned)(p + 1);
        if (tid < 64) {
            if (active) asm volatile("s_waitcnt vmcnt(0)" ::: "memory");
            if (tid == 0)
                __hip_atomic_store(&fl[cgb * 16], tgt, __ATOMIC_RELAXED,
                                   __HIP_MEMORY_SCOPE_AGENT);
        }
        // ---- per-layer master aggregation (block cgb==0, wave 0) ----
        if (cgb == 0 && tid < 64) {
            for (;;) {
                bool ok = (__hip_atomic_load(&fl[lane * 16], __ATOMIC_RELAXED,
                                             __HIP_MEMORY_SCOPE_AGENT) >= tgt)
                       && (__hip_atomic_load(&fl[(lane + 64) * 16], __ATOMIC_RELAXED,
                                             __HIP_MEMORY_SCOPE_AGENT) >= tgt);
                if (__all(ok)) break;
                __builtin_amdgcn_s_sleep(1);
            }
            if (tid == 0)
                __hip_atomic_store(goMine, tgt, __ATOMIC_RELAXED,
                                   __HIP_MEMORY_SCOPE_AGENT);
        }
    }
}

// ---------------------------------------------------------------------------
// Kernel 3: out[b][o] = tanh(h1[b,:] @ Wo[:,o] + bo[o]); h1 in fp16 A-frag.
// ---------------------------------------------------------------------------
__global__ __launch_bounds__(128) void k_out(
    const f16* __restrict__ h1f, const float* __restrict__ Wo,
    const float* __restrict__ bo, float* __restrict__ out)
{
    __shared__ float hs[HH];
    const int b = blockIdx.x;
    for (int i = threadIdx.x; i < HH; i += 128) hs[i] = (float)h1f[afrag_off(b, i)];
    __syncthreads();
    const int o = threadIdx.x;
    float acc = 0.f;
    for (int k = 0; k < HH; ++k) acc += hs[k] * Wo[k * DOUT + o];
    out[b * DOUT + o] = tanhf(acc + bo[o]);
}

// ---------------------------------------------------------------------------
extern "C" void kernel_launch(void* const* d_in, const int* in_sizes, int n_in,
                              void* d_out, int out_size, void* d_ws, size_t ws_size,
                              hipStream_t stream)
{
    const float* x  = (const float*)d_in[0];
    const float* Wi = (const float*)d_in[1];
    const float* bi = (const float*)d_in[2];
    const float* W0 = (const float*)d_in[3];
    const float* U0 = (const float*)d_in[4];
    const float* b0 = (const float*)d_in[5];
    const float* W1 = (const float*)d_in[6];
    const float* U1 = (const float*)d_in[7];
    const float* b1 = (const float*)d_in[8];
    const float* Wo = (const float*)d_in[9];
    const float* bo = (const float*)d_in[10];
    float* out = (float*)d_out;

    f16* ws16 = (f16*)d_ws;
    const size_t HBUF = (size_t)BB * DIN;          // 65536 f16
    f16* XinF = ws16;                              // 512 bufs
    f16* pW0  = XinF + (size_t)TT * HBUF;
    f16* pW1  = pW0 + (size_t)2048 * G4;
    f16* pWi  = pW1 + (size_t)2048 * G4;           // 512*1024
    f16* h0   = pWi + (size_t)FF * DIN;            // 513 bufs (write-once hist)
    f16* h1   = h0 + (size_t)513 * HBUF;           // 513 bufs
    unsigned* flags = (unsigned*)(h1 + (size_t)513 * HBUF);

    // zero initial h0[-1], h1[-1] and the flag region
    hipMemsetAsync(h0, 0, HBUF * sizeof(f16), stream);
    hipMemsetAsync(h1, 0, HBUF * sizeof(f16), stream);
    hipMemsetAsync(flags, 0, 32768, stream);

    k_pack<<<dim3(64, 256), 64, 0, stream>>>(W0, U0, pW0);
    k_pack<<<dim3(64, 256), 64, 0, stream>>>(W1, U1, pW1);
    k_pack_wi<<<dim3(16, 64), 64, 0, stream>>>(Wi, pWi);

    hipFuncSetAttribute((const void*)k_dense_in2,
                        hipFuncAttributeMaxDynamicSharedMemorySize, 66560);
    k_dense_in2<<<TT, 256, 66560, stream>>>(x, pWi, bi, XinF);

    {
        const int smem_bytes = 131072 + 16640 + 1024;   // 148736 B
        hipFuncSetAttribute((const void*)k_persist,
                            hipFuncAttributeMaxDynamicSharedMemorySize, smem_bytes);
        const f16* XinF_c = XinF;
        const f16* pW0_c = pW0;
        const f16* pW1_c = pW1;
        f16 *h0_v = h0, *h1_v = h1;
        const float *b0_v = b0, *b1_v = b1;
        unsigned* flags_v = flags;
        void* kargs[] = {
            (void*)&XinF_c,
            (void*)&h0_v, (void*)&h1_v,
            (void*)&pW0_c, (void*)&pW1_c,
            (void*)&b0_v, (void*)&b1_v,
            (void*)&flags_v
        };
        hipLaunchCooperativeKernel((void*)k_persist, dim3(256), dim3(512),
                                   kargs, smem_bytes, stream);
    }

    // h1[511] lives at h1 + 512*HBUF
    k_out<<<BB, 128, 0, stream>>>(h1 + (size_t)512 * HBUF, Wo, bo, out);
}

// Round 10
// 4306.334 us; speedup vs baseline: 1.0102x; 1.0102x over previous
//
#include <hip/hip_runtime.h>
#include <math.h>

#define BB 64
#define TT 512
#define FF 512
#define DIN 1024
#define HH 1024
#define G4 4096
#define DOUT 128

typedef _Float16 f16;
typedef _Float16 f16x4 __attribute__((ext_vector_type(4)));
typedef _Float16 f16x8 __attribute__((ext_vector_type(8)));
typedef float f32x4 __attribute__((ext_vector_type(4)));

// A-fragment-linear layout for a [64 x 1024] fp16 activation matrix:
//   element (m, k) -> ((k>>5)*4 + (m>>4))*512 + ((((k>>3)&3)<<4) | (m&15))*8 + (k&7)
__device__ __forceinline__ size_t afrag_off(int m, int k) {
    return (size_t)(((k >> 5) * 4 + (m >> 4)) * 512 + (((((k >> 3) & 3) << 4) | (m & 15)) * 8) + (k & 7));
}

// agent-scope write-through 16-B store (IF authoritative for cross-XCD readers)
__device__ __forceinline__ void store_b128_sc1(void* p, f32x4 v) {
    asm volatile("global_store_dwordx4 %0, %1, off sc1" :: "v"(p), "v"(v) : "memory");
}

// spin until *w >= tgt (agent scope)
__device__ __forceinline__ void wave_wait(const unsigned* w, unsigned tgt) {
    while (__hip_atomic_load(w, __ATOMIC_RELAXED, __HIP_MEMORY_SCOPE_AGENT) < tgt)
        __builtin_amdgcn_s_sleep(1);
}

// ---------------------------------------------------------------------------
// Pack cat(W,U) [2048 x 4096] fp32 -> fp16 B-fragment-linear, z-cols reordered
// as col' = j*4 + g. Per (cg, kstep) a contiguous 1KB fragment tile.
// ---------------------------------------------------------------------------
__global__ __launch_bounds__(64) void k_pack(
    const float* __restrict__ W, const float* __restrict__ U, f16* __restrict__ out)
{
    const int kstep = blockIdx.x, cg = blockIdx.y, l = threadIdx.x;
    const int n = l & 15, q = l >> 4;
    const int stdcol = (n & 3) * HH + cg * 4 + (n >> 2);
    f16x8 v;
#pragma unroll
    for (int e = 0; e < 8; ++e) {
        int k = kstep * 32 + q * 8 + e;
        float s = (k < DIN) ? W[(size_t)k * G4 + stdcol] : U[(size_t)(k - DIN) * G4 + stdcol];
        v[e] = (f16)s;
    }
    *(f16x8*)(out + ((size_t)(cg * 64 + kstep) * 64 + l) * 8) = v;
}

// ---------------------------------------------------------------------------
// Pack Wi [512 x 1024] fp32 -> fp16 B-frag (no gate reorder). Tile (nt, kstep).
// ---------------------------------------------------------------------------
__global__ __launch_bounds__(64) void k_pack_wi(
    const float* __restrict__ Wi, f16* __restrict__ out)
{
    const int kstep = blockIdx.x;   // 0..15
    const int nt    = blockIdx.y;   // 0..63
    const int l = threadIdx.x;
    const int n = nt * 16 + (l & 15), q = l >> 4;
    f16x8 v;
#pragma unroll
    for (int e = 0; e < 8; ++e)
        v[e] = (f16)Wi[(size_t)(kstep * 32 + q * 8 + e) * DIN + n];
    *(f16x8*)(out + ((size_t)(nt * 16 + kstep) * 64 + l) * 8) = v;
}

// ---------------------------------------------------------------------------
// MFMA input dense: XinF[t] = tanh(x[:,t,:] @ Wi + bi), f16 A-frag layout.
// ---------------------------------------------------------------------------
__global__ __launch_bounds__(256) void k_dense_in2(
    const float* __restrict__ x, const f16* __restrict__ pWi,
    const float* __restrict__ bi, f16* __restrict__ XinF)
{
    extern __shared__ f16 xs[];   // 64 x 520 = 66560 B
    const int t = blockIdx.x;
    const int tid = threadIdx.x;

#pragma unroll
    for (int it = 0; it < 32; ++it) {
        int idx = tid + it * 256;
        int r = idx >> 7, c4 = idx & 127;
        float4 v = *(const float4*)(x + ((size_t)r * TT + t) * FF + c4 * 4);
        f16x4 hv = {(f16)v.x, (f16)v.y, (f16)v.z, (f16)v.w};
        *(f16x4*)(xs + (size_t)r * 520 + c4 * 4) = hv;
    }
    __syncthreads();

    const int w = tid >> 6, lane = tid & 63;
    const int col = lane & 15, rq = lane >> 4;
#pragma unroll 1
    for (int g = 0; g < 4; ++g) {
        f32x4 acc[4][4];
#pragma unroll
        for (int a = 0; a < 4; ++a)
#pragma unroll
            for (int b = 0; b < 4; ++b) acc[a][b] = (f32x4){0.f, 0.f, 0.f, 0.f};
#pragma unroll 2
        for (int ks2 = 0; ks2 < 16; ++ks2) {
            f16x8 bf[4];
#pragma unroll
            for (int nn = 0; nn < 4; ++nn)
                bf[nn] = *(const f16x8*)(pWi + ((size_t)((w * 16 + g * 4 + nn) * 16 + ks2) * 64 + lane) * 8);
#pragma unroll
            for (int mt = 0; mt < 4; ++mt) {
                f16x8 af = *(const f16x8*)(xs + (size_t)(mt * 16 + col) * 520 + ks2 * 32 + rq * 8);
#pragma unroll
                for (int nn = 0; nn < 4; ++nn)
                    acc[mt][nn] = __builtin_amdgcn_mfma_f32_16x16x32_f16(af, bf[nn], acc[mt][nn], 0, 0, 0);
            }
        }
#pragma unroll
        for (int nn = 0; nn < 4; ++nn) {
            const int j = (w * 16 + g * 4 + nn) * 16 + col;
            const float bb = bi[j];
#pragma unroll
            for (int mt = 0; mt < 4; ++mt)
#pragma unroll
                for (int r = 0; r < 4; ++r)
                    XinF[(size_t)t * (BB * DIN) + afrag_off(mt * 16 + rq * 4 + r, j)]
                        = (f16)tanhf(acc[mt][nn][r] + bb);
        }
    }
}

// ---------------------------------------------------------------------------
// Persistent kernel, 256 blocks x 512 threads (1 block/CU).
// lay = bid&1, cgb = bid>>1 (8 hidden units = 2 N-tiles). Weights in LDS once.
// ONE OUTPUT TILE PER WAVE: wave wv -> (mt = wv&3, jt = wv>>2), K=2048 full,
// 2 independent MFMA chains per K-half. No cross-wave K-reduce.
// Static K-half (L0: Xin; L1: h1[p-2] after early go1) computed BEFORE the
// go0 gate; only the h0-half is post-trigger. Gate fan-out: wave0 lane0 polls
// the IF go word, publishes to an LDS gate; other waves spin on LDS.
// Epilogue: wave-private C->LDS, per-lane gate math (512 lanes parallel),
// shfl-pair h halves into LDS words; ONE __syncthreads; wave1 does 64 16-B
// sc1 stores + vmcnt drain + arrival flag. Per-layer master (cgb0, wave0)
// aggregates 128 arrivals, publishes go. c state in registers (1/lane).
// ---------------------------------------------------------------------------
__global__ __launch_bounds__(512, 2) void k_persist(
    const f16* __restrict__ XinF,
    f16* __restrict__ h0b_, f16* __restrict__ h1b_,
    const f16* __restrict__ pW0, const f16* __restrict__ pW1,
    const float* __restrict__ b0, const float* __restrict__ b1,
    unsigned* __restrict__ flags)
{
    extern __shared__ char smem[];
    f16*   bsh  = (f16*)smem;                       // 131072 B weight fragments
    float* cw   = (float*)(smem + 131072);          // 8 waves x 320 floats
    f16*   hrow = (f16*)(smem + 141312);            // 64 rows x 8 halves
    unsigned* gates = (unsigned*)(smem + 142336);   // [0]=gate0(go0) [1]=gate1(go1)

    const int lay = blockIdx.x & 1;
    const int cgb = blockIdx.x >> 1;
    const int tid = threadIdx.x;
    const int wv = tid >> 6, lane = tid & 63;
    const int mt = wv & 3, jt = wv >> 2;

    unsigned* fl  = flags + (lay ? 2048 : 0);       // own-layer arrivals, stride 16
    unsigned* go0 = flags + 4096;
    unsigned* go1 = flags + 4096 + 16;
    unsigned* goMine = lay ? go1 : go0;

    // ---- stage this block's weight slice into LDS (once) ----
    {
        const f16x8* s8 = (const f16x8*)((lay ? pW1 : pW0) + (size_t)(cgb * 2) * 64 * 512);
        f16x8* d8 = (f16x8*)bsh;
#pragma unroll
        for (int it = 0; it < 16; ++it) d8[tid + it * 512] = s8[tid + it * 512];
    }
    if (tid == 0) { gates[0] = 0; gates[1] = 0; }

    // ---- per-lane epilogue constants: lane -> (row = lane&15, jj = lane>>4) ----
    const int erow = lane & 15, ejj = lane >> 4;
    const int jglob = cgb * 8 + jt * 4 + ejj;
    const float* bias = lay ? b1 : b0;
    float bz[4];
#pragma unroll
    for (int g = 0; g < 4; ++g) bz[g] = bias[g * HH + jglob];
    float creg = 0.f;
    float* cwv = cw + wv * 320;

    const size_t HBUF = (size_t)BB * DIN;
    volatile unsigned* vg = gates;
    __syncthreads();

    for (int p = 0; p <= TT; ++p) {
        if (lay == 0 && p == TT) break;             // L0 does phases 0..511
        const bool active = lay ? (p >= 1) : true;

        if (active) {
            const f16* firstA  = lay ? (h1b_ + (size_t)(p - 1) * HBUF)
                                     : (XinF + (size_t)p * HBUF);
            const f16* secondA = h0b_ + (size_t)p * HBUF;     // h0[p-1]
            f16* hw = lay ? (h1b_ + (size_t)p * HBUF)
                          : (h0b_ + (size_t)(p + 1) * HBUF);

            // ---- gate for first half (L1 only: h1[p-2] needs go1 >= p) ----
            if (lay) {
                if (wv == 0) {
                    if (lane == 0) { wave_wait(go1, (unsigned)p); vg[1] = (unsigned)p; }
                } else {
                    if (lane == 0) { while (vg[1] < (unsigned)p) __builtin_amdgcn_s_sleep(1); }
                }
            }

            f32x4 ac0 = {0.f,0.f,0.f,0.f}, ac1 = {0.f,0.f,0.f,0.f};
            f32x4 ac2 = {0.f,0.f,0.f,0.f}, ac3 = {0.f,0.f,0.f,0.f};

            // ---- first K-half (pre-trigger) ----
            {
                const f16* Ap = firstA + (size_t)(mt * 512) + (size_t)lane * 8;
                const f16* Bp = bsh + (size_t)((jt * 64 + (lay ? 32 : 0)) * 512) + (size_t)lane * 8;
#pragma unroll
                for (int ks = 0; ks < 32; ks += 2) {
                    f16x8 a0 = *(const f16x8*)(Ap + (size_t)ks * 2048);
                    f16x8 a1 = *(const f16x8*)(Ap + (size_t)(ks + 1) * 2048);
                    f16x8 b0v = *(const f16x8*)(Bp + (size_t)ks * 512);
                    f16x8 b1v = *(const f16x8*)(Bp + (size_t)(ks + 1) * 512);
                    ac0 = __builtin_amdgcn_mfma_f32_16x16x32_f16(a0, b0v, ac0, 0, 0, 0);
                    ac1 = __builtin_amdgcn_mfma_f32_16x16x32_f16(a1, b1v, ac1, 0, 0, 0);
                }
            }

            // ---- gate for second half: h0[p-1] needs go0 >= p ----
            if (!(lay == 0 && p == 0)) {
                if (wv == 0) {
                    if (lane == 0) { wave_wait(go0, (unsigned)p); vg[0] = (unsigned)p; }
                } else {
                    if (lane == 0) { while (vg[0] < (unsigned)p) __builtin_amdgcn_s_sleep(1); }
                }
            }

            // ---- second K-half (post-trigger) ----
            {
                const f16* Ap = secondA + (size_t)(mt * 512) + (size_t)lane * 8;
                const f16* Bp = bsh + (size_t)((jt * 64 + (lay ? 0 : 32)) * 512) + (size_t)lane * 8;
#pragma unroll
                for (int ks = 0; ks < 32; ks += 2) {
                    f16x8 a0 = *(const f16x8*)(Ap + (size_t)ks * 2048);
                    f16x8 a1 = *(const f16x8*)(Ap + (size_t)(ks + 1) * 2048);
                    f16x8 b0v = *(const f16x8*)(Bp + (size_t)ks * 512);
                    f16x8 b1v = *(const f16x8*)(Bp + (size_t)(ks + 1) * 512);
                    ac2 = __builtin_amdgcn_mfma_f32_16x16x32_f16(a0, b0v, ac2, 0, 0, 0);
                    ac3 = __builtin_amdgcn_mfma_f32_16x16x32_f16(a1, b1v, ac3, 0, 0, 0);
                }
            }

            // ---- wave-private epilogue: C -> LDS, per-lane gate math ----
            {
                f32x4 z4 = (ac0 + ac1) + (ac2 + ac3);
                const int col = lane & 15, q = lane >> 4;
                *(f32x4*)(cwv + col * 20 + q * 4) = z4;   // C[row][col] at cwv[col*20+row]
            }
            float z[4];
#pragma unroll
            for (int g = 0; g < 4; ++g)
                z[g] = cwv[(ejj * 4 + g) * 20 + erow] + bz[g];
            const float ig = 1.f / (1.f + expf(-z[0]));
            const float fg = 1.f / (1.f + expf(-z[1]));
            const float cc = tanhf(z[2]);
            const float og = 1.f / (1.f + expf(-z[3]));
            const float cn = fg * creg + ig * cc;
            creg = cn;
            const f16 hval = (f16)(og * tanhf(cn));

            // ---- shfl-pair h halves (jj, jj+1) into one LDS word ----
            {
                int hv = (int)(unsigned)__builtin_bit_cast(unsigned short, hval);
                int other = __shfl_down(hv, 16);
                if ((ejj & 1) == 0)
                    *(unsigned*)&hrow[(mt * 16 + erow) * 8 + jt * 4 + ejj]
                        = (unsigned)hv | ((unsigned)other << 16);
            }
            __syncthreads();

            // ---- wave 1: 64 x 16-B sc1 row stores ----
            if (wv == 1) {
                f32x4 v = *(f32x4*)(hrow + (size_t)lane * 8);
                store_b128_sc1(hw + afrag_off(lane, cgb * 8), v);
            }
        }

        // ---- arrival (wave 1: drain own stores, then flag) ----
        const unsigned tgt = (unsigned)(p + 1);
        if (wv == 1) {
            if (active) asm volatile("s_waitcnt vmcnt(0)" ::: "memory");
            if (lane == 0)
                __hip_atomic_store(&fl[cgb * 16], tgt, __ATOMIC_RELAXED,
                                   __HIP_MEMORY_SCOPE_AGENT);
        }
        // ---- per-layer master aggregation (cgb==0, wave 0) ----
        if (cgb == 0 && wv == 0) {
            for (;;) {
                bool ok = (__hip_atomic_load(&fl[lane * 16], __ATOMIC_RELAXED,
                                             __HIP_MEMORY_SCOPE_AGENT) >= tgt)
                       && (__hip_atomic_load(&fl[(lane + 64) * 16], __ATOMIC_RELAXED,
                                             __HIP_MEMORY_SCOPE_AGENT) >= tgt);
                if (__all(ok)) break;
                __builtin_amdgcn_s_sleep(1);
            }
            if (lane == 0)
                __hip_atomic_store(goMine, tgt, __ATOMIC_RELAXED,
                                   __HIP_MEMORY_SCOPE_AGENT);
        }
    }
}

// ---------------------------------------------------------------------------
// Kernel 3: out[b][o] = tanh(h1[b,:] @ Wo[:,o] + bo[o]); h1 in fp16 A-frag.
// ---------------------------------------------------------------------------
__global__ __launch_bounds__(128) void k_out(
    const f16* __restrict__ h1f, const float* __restrict__ Wo,
    const float* __restrict__ bo, float* __restrict__ out)
{
    __shared__ float hs[HH];
    const int b = blockIdx.x;
    for (int i = threadIdx.x; i < HH; i += 128) hs[i] = (float)h1f[afrag_off(b, i)];
    __syncthreads();
    const int o = threadIdx.x;
    float acc = 0.f;
    for (int k = 0; k < HH; ++k) acc += hs[k] * Wo[k * DOUT + o];
    out[b * DOUT + o] = tanhf(acc + bo[o]);
}

// ---------------------------------------------------------------------------
extern "C" void kernel_launch(void* const* d_in, const int* in_sizes, int n_in,
                              void* d_out, int out_size, void* d_ws, size_t ws_size,
                              hipStream_t stream)
{
    const float* x  = (const float*)d_in[0];
    const float* Wi = (const float*)d_in[1];
    const float* bi = (const float*)d_in[2];
    const float* W0 = (const float*)d_in[3];
    const float* U0 = (const float*)d_in[4];
    const float* b0 = (const float*)d_in[5];
    const float* W1 = (const float*)d_in[6];
    const float* U1 = (const float*)d_in[7];
    const float* b1 = (const float*)d_in[8];
    const float* Wo = (const float*)d_in[9];
    const float* bo = (const float*)d_in[10];
    float* out = (float*)d_out;

    f16* ws16 = (f16*)d_ws;
    const size_t HBUF = (size_t)BB * DIN;          // 65536 f16
    f16* XinF = ws16;                              // 512 bufs
    f16* pW0  = XinF + (size_t)TT * HBUF;
    f16* pW1  = pW0 + (size_t)2048 * G4;
    f16* pWi  = pW1 + (size_t)2048 * G4;           // 512*1024
    f16* h0   = pWi + (size_t)FF * DIN;            // 513 bufs (write-once hist)
    f16* h1   = h0 + (size_t)513 * HBUF;           // 513 bufs
    unsigned* flags = (unsigned*)(h1 + (size_t)513 * HBUF);

    // zero initial h0[-1], h1[-1] and the flag region
    hipMemsetAsync(h0, 0, HBUF * sizeof(f16), stream);
    hipMemsetAsync(h1, 0, HBUF * sizeof(f16), stream);
    hipMemsetAsync(flags, 0, 32768, stream);

    k_pack<<<dim3(64, 256), 64, 0, stream>>>(W0, U0, pW0);
    k_pack<<<dim3(64, 256), 64, 0, stream>>>(W1, U1, pW1);
    k_pack_wi<<<dim3(16, 64), 64, 0, stream>>>(Wi, pWi);

    hipFuncSetAttribute((const void*)k_dense_in2,
                        hipFuncAttributeMaxDynamicSharedMemorySize, 66560);
    k_dense_in2<<<TT, 256, 66560, stream>>>(x, pWi, bi, XinF);

    {
        const int smem_bytes = 142400;   // bsh 131072 + cw 10240 + hrow 1024 + gates
        hipFuncSetAttribute((const void*)k_persist,
                            hipFuncAttributeMaxDynamicSharedMemorySize, smem_bytes);
        const f16* XinF_c = XinF;
        const f16* pW0_c = pW0;
        const f16* pW1_c = pW1;
        f16 *h0_v = h0, *h1_v = h1;
        const float *b0_v = b0, *b1_v = b1;
        unsigned* flags_v = flags;
        void* kargs[] = {
            (void*)&XinF_c,
            (void*)&h0_v, (void*)&h1_v,
            (void*)&pW0_c, (void*)&pW1_c,
            (void*)&b0_v, (void*)&b1_v,
            (void*)&flags_v
        };
        hipLaunchCooperativeKernel((void*)k_persist, dim3(256), dim3(512),
                                   kargs, smem_bytes, stream);
    }

    // h1[511] lives at h1 + 512*HBUF
    k_out<<<BB, 128, 0, stream>>>(h1 + (size_t)512 * HBUF, Wo, bo, out);
}